// Round 1
// baseline (382.310 us; speedup 1.0000x reference)
//
#include <hip/hip_runtime.h>
#include <hip/hip_bf16.h>

// GCN encoder: z = relu(A @ relu(A @ (x@W1) + b1) @ W2 + b2)
// R7: pipeline the GEMMs (T3-minimal 1-deep prefetch). R6's k_gemm1 was fully
// serial per K-step (load->drain->compute->barrier): MfmaUtil 7.8%, HBM 27%,
// occupancy 16% -> latency-bound, 3x above the 20us BW floor. Now: LDS double
// buffered (sA/sB x2, 64KB), next tile's A-reg loads + B global_load_lds issued
// BEFORE the MFMA phase, A cvt+ds_write into the other buffer AFTER, single
// barrier per K-step. Same for gemm2 (both operands gll16).

typedef __attribute__((ext_vector_type(8))) short bf16x8;
typedef __attribute__((ext_vector_type(8))) unsigned short ushort8;
typedef __attribute__((ext_vector_type(4))) float f32x4;

#define NN 50000
#define NE 800000
#define NF 512
#define NH 256
#define NL 128
#define NB ((NN + 255) / 256)

static __device__ __forceinline__ unsigned short f2bf(float f) {
  union { float f; unsigned int u; } v; v.f = f;
  unsigned int r = v.u + 0x7fffu + ((v.u >> 16) & 1u);   // RNE
  return (unsigned short)(r >> 16);
}
static __device__ __forceinline__ float bf2f(unsigned short u) {
  union { unsigned int u; float f; } v; v.u = (unsigned int)u << 16;
  return v.f;
}

static __device__ __forceinline__ ushort8 cvt8(float4 a, float4 b) {
  ushort8 o;
  o[0] = f2bf(a.x); o[1] = f2bf(a.y); o[2] = f2bf(a.z); o[3] = f2bf(a.w);
  o[4] = f2bf(b.x); o[5] = f2bf(b.y); o[6] = f2bf(b.z); o[7] = f2bf(b.w);
  return o;
}

// async global->LDS, 16B/lane; LDS dest must be wave-uniform base + lane*16.
static __device__ __forceinline__ void gll16(const void* g, void* l) {
  __builtin_amdgcn_global_load_lds(
      (const __attribute__((address_space(1))) void*)g,
      (__attribute__((address_space(3))) void*)l, 16, 0, 0);
}

// ---------------- CSR build ----------------
extern "C" __global__ void k_hist(const int* __restrict__ rows, int* __restrict__ counts, int n) {
  int i = blockIdx.x * 256 + threadIdx.x;
  if (i < n) atomicAdd(&counts[rows[i]], 1);
}

extern "C" __global__ __launch_bounds__(256) void k_blocksum(
    const int* __restrict__ counts, int* __restrict__ bsum, int n) {
  __shared__ int s[256];
  int t = threadIdx.x;
  int i = blockIdx.x * 256 + t;
  s[t] = (i < n) ? counts[i] : 0;
  __syncthreads();
  for (int off = 128; off > 0; off >>= 1) {
    if (t < off) s[t] += s[t + off];
    __syncthreads();
  }
  if (t == 0) bsum[blockIdx.x] = s[0];
}

extern "C" __global__ __launch_bounds__(256) void k_scansums(
    const int* __restrict__ bsum, int* __restrict__ bpre, int* __restrict__ rp, int nb, int n) {
  __shared__ int s[256];
  int t = threadIdx.x;
  int v = (t < nb) ? bsum[t] : 0;
  s[t] = v;
  __syncthreads();
  for (int off = 1; off < 256; off <<= 1) {
    int u = (t >= off) ? s[t - off] : 0;
    __syncthreads();
    s[t] += u;
    __syncthreads();
  }
  if (t < nb) bpre[t] = s[t] - v;
  if (t == 255) rp[n] = s[255];
}

extern "C" __global__ __launch_bounds__(256) void k_scanfin(
    const int* __restrict__ counts, const int* __restrict__ bpre,
    int* __restrict__ rp, int* __restrict__ cur, int n) {
  __shared__ int s[256];
  int t = threadIdx.x;
  int i = blockIdx.x * 256 + t;
  int c = (i < n) ? counts[i] : 0;
  s[t] = c;
  __syncthreads();
  for (int off = 1; off < 256; off <<= 1) {
    int u = (t >= off) ? s[t - off] : 0;
    __syncthreads();
    s[t] += u;
    __syncthreads();
  }
  if (i < n) {
    int e = bpre[blockIdx.x] + s[t] - c;
    rp[i] = e;
    cur[i] = e;
  }
}

extern "C" __global__ void k_scatter(const int* __restrict__ rows, const int* __restrict__ cols,
    const float* __restrict__ vals, int* __restrict__ cur, int2* __restrict__ ep, int n) {
  int i = blockIdx.x * 256 + threadIdx.x;
  if (i < n) {
    int p = atomicAdd(&cur[rows[i]], 1);
    int2 e; e.x = cols[i]; e.y = __float_as_int(vals[i]);
    ep[p] = e;
  }
}

// ---------------- weight transpose-cast: W [K][N] fp32 -> WT [N][K] bf16 ----------------
extern "C" __global__ void k_transcast(const float* __restrict__ w, unsigned short* __restrict__ wt,
                                       int K, int N) {
  int k = blockIdx.x; int n = threadIdx.x;
  wt[(size_t)n * K + k] = f2bf(w[(size_t)k * N + n]);
}

// ---------------- GEMM1: C[NN][256] = x[NN][512](fp32) * W1T[256][512]^T, bf16 out ----------------
// BM=128 BN=128 BK=64; pipelined: A via register prefetch (swizzled ds_write into
// the non-current buffer post-MFMA), B via gll16 with swizzled GLOBAL source into
// the non-current buffer pre-MFMA. One barrier per K-step.
extern "C" __global__ __launch_bounds__(256) void k_gemm1(
    const float* __restrict__ A, const unsigned short* __restrict__ BT,
    unsigned short* __restrict__ C) {
  __shared__ __align__(16) unsigned short sA[2][128 * 64];
  __shared__ __align__(16) unsigned short sB[2][128 * 64];
  int tid = threadIdx.x;
  int lane = tid & 63, wid = tid >> 6;
  int wm = (wid >> 1) * 64, wn = (wid & 1) * 64;
  int bm = blockIdx.x * 128, bn = blockIdx.y * 128;
  int l15 = lane & 15, lq = lane >> 4;
  int swzbase = l15 & 7;                  // row&7 for all fragment rows this lane reads
  f32x4 acc[4][4];
#pragma unroll
  for (int i = 0; i < 4; ++i)
#pragma unroll
    for (int j = 0; j < 4; ++j) acc[i][j] = (f32x4){0.f, 0.f, 0.f, 0.f};

  // Per-thread staging geometry (4 16B-units each for A and B):
  // unit u = tid + 256*j: row = u>>3, cu = u&7.
  // A: read 32B fp32 at (bm+row, k0 + cu*8), write bf16 to sA unit cu^(row&7).
  // B: LDS stays contiguous (gll16); fetch global unit g = cu^(row&7).
  float4 ra[4][2];

  // ---- prologue: tile 0 ----
#pragma unroll
  for (int j = 0; j < 4; ++j) {
    int u = tid + 256 * j;
    int row = u >> 3, cu = u & 7;
    int ga = bm + row; if (ga >= NN) ga = NN - 1;
    const float* src = A + (size_t)ga * NF + cu * 8;
    ra[j][0] = ((const float4*)src)[0];
    ra[j][1] = ((const float4*)src)[1];
  }
#pragma unroll
  for (int j = 0; j < 4; ++j) {
    int u = tid + 256 * j;
    int row = u >> 3, cu = u & 7;
    int g = cu ^ (row & 7);
    gll16(BT + (size_t)(bn + row) * NF + g * 8, &sB[0][u * 8]);
  }
#pragma unroll
  for (int j = 0; j < 4; ++j) {
    int u = tid + 256 * j;
    int row = u >> 3, cu = u & 7;
    *(ushort8*)(&sA[0][row * 64 + (cu ^ (row & 7)) * 8]) = cvt8(ra[j][0], ra[j][1]);
  }
  __syncthreads();

  int cur = 0;
  for (int t = 0; t < NF / 64; ++t) {
    int k1 = (t + 1) * 64;
    if (t < NF / 64 - 1) {
      // issue next A tile into registers (in flight across the MFMA phase)
#pragma unroll
      for (int j = 0; j < 4; ++j) {
        int u = tid + 256 * j;
        int row = u >> 3, cu = u & 7;
        int ga = bm + row; if (ga >= NN) ga = NN - 1;
        const float* src = A + (size_t)ga * NF + k1 + cu * 8;
        ra[j][0] = ((const float4*)src)[0];
        ra[j][1] = ((const float4*)src)[1];
      }
      // issue next B tile into the other LDS buffer
#pragma unroll
      for (int j = 0; j < 4; ++j) {
        int u = tid + 256 * j;
        int row = u >> 3, cu = u & 7;
        int g = cu ^ (row & 7);
        gll16(BT + (size_t)(bn + row) * NF + k1 + g * 8, &sB[cur ^ 1][u * 8]);
      }
    }
    // compute on current buffers
#pragma unroll
    for (int ks = 0; ks < 64; ks += 32) {
      bf16x8 af[4], bfr[4];
#pragma unroll
      for (int tt = 0; tt < 4; ++tt) {
        int sz = (((ks >> 3) + lq) ^ swzbase) * 8;
        af[tt]  = *(const bf16x8*)(&sA[cur][(wm + tt * 16 + l15) * 64 + sz]);
        bfr[tt] = *(const bf16x8*)(&sB[cur][(wn + tt * 16 + l15) * 64 + sz]);
      }
#pragma unroll
      for (int mt = 0; mt < 4; ++mt)
#pragma unroll
        for (int nt = 0; nt < 4; ++nt)
          acc[mt][nt] = __builtin_amdgcn_mfma_f32_16x16x32_bf16(af[mt], bfr[nt], acc[mt][nt], 0, 0, 0);
    }
    // convert + write next A tile into the other buffer (reads of it finished
    // at the previous barrier)
    if (t < NF / 64 - 1) {
#pragma unroll
      for (int j = 0; j < 4; ++j) {
        int u = tid + 256 * j;
        int row = u >> 3, cu = u & 7;
        *(ushort8*)(&sA[cur ^ 1][row * 64 + (cu ^ (row & 7)) * 8]) = cvt8(ra[j][0], ra[j][1]);
      }
    }
    __syncthreads();
    cur ^= 1;
  }
#pragma unroll
  for (int mt = 0; mt < 4; ++mt) {
#pragma unroll
    for (int r = 0; r < 4; ++r) {
      int gr = bm + wm + mt * 16 + lq * 4 + r;
      if (gr < NN) {
#pragma unroll
        for (int nt = 0; nt < 4; ++nt) {
          int gc = bn + wn + nt * 16 + l15;
          C[(size_t)gr * NH + gc] = f2bf(acc[mt][nt][r]);
        }
      }
    }
  }
}

// ---------------- GEMM2: C[NN][128] = h[NN][256](bf16) * W2T[128][256]^T, bf16 out ----------------
// BM=64 BN=128 BK=64; both operands via gll16 with swizzled global source;
// pipelined double-buffer, one barrier per K-step.
extern "C" __global__ __launch_bounds__(256) void k_gemm2(
    const unsigned short* __restrict__ A, const unsigned short* __restrict__ BT,
    unsigned short* __restrict__ C) {
  __shared__ __align__(16) unsigned short sA[2][64 * 64];
  __shared__ __align__(16) unsigned short sB[2][128 * 64];
  int tid = threadIdx.x;
  int lane = tid & 63, wid = tid >> 6;
  int wm = (wid >> 1) * 32, wn = (wid & 1) * 64;
  int bm = blockIdx.x * 64;
  int l15 = lane & 15, lq = lane >> 4;
  int swzbase = l15 & 7;
  f32x4 acc[2][4];
#pragma unroll
  for (int i = 0; i < 2; ++i)
#pragma unroll
    for (int j = 0; j < 4; ++j) acc[i][j] = (f32x4){0.f, 0.f, 0.f, 0.f};

  // ---- prologue: tile 0 ----
#pragma unroll
  for (int j = 0; j < 2; ++j) {
    int u = tid + 256 * j;
    int row = u >> 3, cu = u & 7;
    int ga = bm + row; if (ga >= NN) ga = NN - 1;
    int g = cu ^ (row & 7);
    gll16(A + (size_t)ga * NH + g * 8, &sA[0][u * 8]);
  }
#pragma unroll
  for (int j = 0; j < 4; ++j) {
    int u = tid + 256 * j;
    int row = u >> 3, cu = u & 7;
    int g = cu ^ (row & 7);
    gll16(BT + (size_t)row * NH + g * 8, &sB[0][u * 8]);
  }
  __syncthreads();

  int cur = 0;
  for (int t = 0; t < NH / 64; ++t) {
    int k1 = (t + 1) * 64;
    if (t < NH / 64 - 1) {
#pragma unroll
      for (int j = 0; j < 2; ++j) {
        int u = tid + 256 * j;
        int row = u >> 3, cu = u & 7;
        int ga = bm + row; if (ga >= NN) ga = NN - 1;
        int g = cu ^ (row & 7);
        gll16(A + (size_t)ga * NH + k1 + g * 8, &sA[cur ^ 1][u * 8]);
      }
#pragma unroll
      for (int j = 0; j < 4; ++j) {
        int u = tid + 256 * j;
        int row = u >> 3, cu = u & 7;
        int g = cu ^ (row & 7);
        gll16(BT + (size_t)row * NH + k1 + g * 8, &sB[cur ^ 1][u * 8]);
      }
    }
#pragma unroll
    for (int ks = 0; ks < 64; ks += 32) {
      bf16x8 af[2], bfr[4];
#pragma unroll
      for (int tt = 0; tt < 2; ++tt)
        af[tt] = *(const bf16x8*)(&sA[cur][(wm + tt * 16 + l15) * 64 + (((ks >> 3) + lq) ^ swzbase) * 8]);
#pragma unroll
      for (int tt = 0; tt < 4; ++tt)
        bfr[tt] = *(const bf16x8*)(&sB[cur][(wn + tt * 16 + l15) * 64 + (((ks >> 3) + lq) ^ swzbase) * 8]);
#pragma unroll
      for (int mt = 0; mt < 2; ++mt)
#pragma unroll
        for (int nt = 0; nt < 4; ++nt)
          acc[mt][nt] = __builtin_amdgcn_mfma_f32_16x16x32_bf16(af[mt], bfr[nt], acc[mt][nt], 0, 0, 0);
    }
    __syncthreads();
    cur ^= 1;
  }
#pragma unroll
  for (int mt = 0; mt < 2; ++mt) {
#pragma unroll
    for (int r = 0; r < 4; ++r) {
      int gr = bm + wm + mt * 16 + lq * 4 + r;
      if (gr < NN) {
#pragma unroll
        for (int nt = 0; nt < 4; ++nt) {
          int gc = wn + nt * 16 + l15;
          C[(size_t)gr * NL + gc] = f2bf(acc[mt][nt][r]);
        }
      }
    }
  }
}

// ---------------- SpMM (CSR row-gather), bf16 src, unroll-8/4/1, fused bias+relu ----------------
extern "C" __global__ __launch_bounds__(256) void k_spmm256(
    const int* __restrict__ rp, const int2* __restrict__ ep,
    const unsigned short* __restrict__ src, const float* __restrict__ bias,
    ushort4* __restrict__ out) {
  int row = blockIdx.x * 4 + (threadIdx.x >> 6);
  int lane = threadIdx.x & 63;
  if (row >= NN) return;
  int e0 = __builtin_amdgcn_readfirstlane(rp[row]);
  int e1 = __builtin_amdgcn_readfirstlane(rp[row + 1]);
  const ushort4* srcv = (const ushort4*)src;
  float4 acc = {0.f, 0.f, 0.f, 0.f};
  int e = e0;
  for (; e + 8 <= e1; e += 8) {
    int2 p[8]; ushort4 g[8];
#pragma unroll
    for (int j = 0; j < 8; ++j) p[j] = ep[e + j];
#pragma unroll
    for (int j = 0; j < 8; ++j) g[j] = srcv[(size_t)p[j].x * (NH / 4) + lane];
#pragma unroll
    for (int j = 0; j < 8; ++j) {
      float v = __int_as_float(p[j].y);
      acc.x = fmaf(v, bf2f(g[j].x), acc.x); acc.y = fmaf(v, bf2f(g[j].y), acc.y);
      acc.z = fmaf(v, bf2f(g[j].z), acc.z); acc.w = fmaf(v, bf2f(g[j].w), acc.w);
    }
  }
  for (; e + 4 <= e1; e += 4) {
    int2 p[4]; ushort4 g[4];
#pragma unroll
    for (int j = 0; j < 4; ++j) p[j] = ep[e + j];
#pragma unroll
    for (int j = 0; j < 4; ++j) g[j] = srcv[(size_t)p[j].x * (NH / 4) + lane];
#pragma unroll
    for (int j = 0; j < 4; ++j) {
      float v = __int_as_float(p[j].y);
      acc.x = fmaf(v, bf2f(g[j].x), acc.x); acc.y = fmaf(v, bf2f(g[j].y), acc.y);
      acc.z = fmaf(v, bf2f(g[j].z), acc.z); acc.w = fmaf(v, bf2f(g[j].w), acc.w);
    }
  }
  for (; e < e1; ++e) {
    int2 p = ep[e];
    float v = __int_as_float(p.y);
    ushort4 g = srcv[(size_t)p.x * (NH / 4) + lane];
    acc.x = fmaf(v, bf2f(g.x), acc.x); acc.y = fmaf(v, bf2f(g.y), acc.y);
    acc.z = fmaf(v, bf2f(g.z), acc.z); acc.w = fmaf(v, bf2f(g.w), acc.w);
  }
  float4 b = ((const float4*)bias)[lane];
  ushort4 o;
  o.x = f2bf(fmaxf(acc.x + b.x, 0.f));
  o.y = f2bf(fmaxf(acc.y + b.y, 0.f));
  o.z = f2bf(fmaxf(acc.z + b.z, 0.f));
  o.w = f2bf(fmaxf(acc.w + b.w, 0.f));
  out[(size_t)row * (NH / 4) + lane] = o;
}

extern "C" __global__ __launch_bounds__(256) void k_spmm128(
    const int* __restrict__ rp, const int2* __restrict__ ep,
    const unsigned short* __restrict__ src, const float* __restrict__ bias,
    float2* __restrict__ out) {
  int row = blockIdx.x * 4 + (threadIdx.x >> 6);
  int lane = threadIdx.x & 63;
  if (row >= NN) return;
  int e0 = __builtin_amdgcn_readfirstlane(rp[row]);
  int e1 = __builtin_amdgcn_readfirstlane(rp[row + 1]);
  const ushort2* srcv = (const ushort2*)src;
  float2 acc = {0.f, 0.f};
  int e = e0;
  for (; e + 8 <= e1; e += 8) {
    int2 p[8]; ushort2 g[8];
#pragma unroll
    for (int j = 0; j < 8; ++j) p[j] = ep[e + j];
#pragma unroll
    for (int j = 0; j < 8; ++j) g[j] = srcv[(size_t)p[j].x * (NL / 2) + lane];
#pragma unroll
    for (int j = 0; j < 8; ++j) {
      float v = __int_as_float(p[j].y);
      acc.x = fmaf(v, bf2f(g[j].x), acc.x); acc.y = fmaf(v, bf2f(g[j].y), acc.y);
    }
  }
  for (; e + 4 <= e1; e += 4) {
    int2 p[4]; ushort2 g[4];
#pragma unroll
    for (int j = 0; j < 4; ++j) p[j] = ep[e + j];
#pragma unroll
    for (int j = 0; j < 4; ++j) g[j] = srcv[(size_t)p[j].x * (NL / 2) + lane];
#pragma unroll
    for (int j = 0; j < 4; ++j) {
      float v = __int_as_float(p[j].y);
      acc.x = fmaf(v, bf2f(g[j].x), acc.x); acc.y = fmaf(v, bf2f(g[j].y), acc.y);
    }
  }
  for (; e < e1; ++e) {
    int2 p = ep[e];
    float v = __int_as_float(p.y);
    ushort2 g = srcv[(size_t)p.x * (NL / 2) + lane];
    acc.x = fmaf(v, bf2f(g.x), acc.x); acc.y = fmaf(v, bf2f(g.y), acc.y);
  }
  float2 b = ((const float2*)bias)[lane];
  float2 o;
  o.x = fmaxf(acc.x + b.x, 0.f);
  o.y = fmaxf(acc.y + b.y, 0.f);
  out[(size_t)row * (NL / 2) + lane] = o;
}

// ---------------- launch ----------------
extern "C" void kernel_launch(void* const* d_in, const int* in_sizes, int n_in,
                              void* d_out, int out_size, void* d_ws, size_t ws_size,
                              hipStream_t stream) {
  const float* x   = (const float*)d_in[0];
  const int* erow  = (const int*)d_in[1];
  const int* ecol  = (const int*)d_in[2];
  const float* ev  = (const float*)d_in[3];
  const float* W1  = (const float*)d_in[4];
  const float* b1  = (const float*)d_in[5];
  const float* W2  = (const float*)d_in[6];
  const float* b2  = (const float*)d_in[7];

  char* ws = (char*)d_ws;
  unsigned short* xwb = (unsigned short*)(ws + 0);           // 25,600,000 (x@W1 bf16)
  unsigned short* hbf = (unsigned short*)(ws + 25600000);    // 25,600,000 (h bf16)
  unsigned short* hwb = (unsigned short*)(ws + 51200000);    // 12,800,000 (h@W2 bf16)
  unsigned short* w1t = (unsigned short*)(ws + 64000000);    // 262,144
  unsigned short* w2t = (unsigned short*)(ws + 64262144);    // 65,536
  int* rp    = (int*)(ws + 64327680);                        // 200,704
  int* cur   = (int*)(ws + 64528384);                        // 200,704
  int* cnt   = (int*)(ws + 64729088);                        // 200,704
  int* bsum  = (int*)(ws + 64929792);                        // 1,024
  int* bpre  = (int*)(ws + 64930816);                        // 1,024
  int2* ep   = (int2*)(ws + 64931840);                       // 6,400,000

  // CSR build
  hipMemsetAsync(cnt, 0, NN * sizeof(int), stream);
  k_hist<<<NE / 256, 256, 0, stream>>>(erow, cnt, NE);
  k_blocksum<<<NB, 256, 0, stream>>>(cnt, bsum, NN);
  k_scansums<<<1, 256, 0, stream>>>(bsum, bpre, rp, NB, NN);
  k_scanfin<<<NB, 256, 0, stream>>>(cnt, bpre, rp, cur, NN);
  k_scatter<<<NE / 256, 256, 0, stream>>>(erow, ecol, ev, cur, ep, NE);

  // layer 1
  k_transcast<<<NF, NH, 0, stream>>>(W1, w1t, NF, NH);
  k_gemm1<<<dim3((NN + 127) / 128, NH / 128), 256, 0, stream>>>(x, w1t, xwb);
  k_spmm256<<<NN / 4, 256, 0, stream>>>(rp, ep, xwb, b1, (ushort4*)hbf);

  // layer 2
  k_transcast<<<NH, NL, 0, stream>>>(W2, w2t, NH, NL);
  k_gemm2<<<(NN + 63) / 64, 256, 0, stream>>>(hbf, w2t, hwb);
  k_spmm128<<<NN / 4, 256, 0, stream>>>(rp, ep, hwb, b2, (float2*)d_out);
}

// Round 2
// 380.479 us; speedup vs baseline: 1.0048x; 1.0048x over previous
//
#include <hip/hip_runtime.h>
#include <hip/hip_bf16.h>

// GCN encoder: z = relu(A @ relu(A @ (x@W1) + b1) @ W2 + b2)
// R8: gemm1 rework after the R7 null (1-deep dbuf pipeline = no change; the
// __syncthreads vmcnt(0) drain kills it -- m99/m100 mechanism). Two levers:
//  (a) v_cvt_pk_bf16_f32 for the fp32->bf16 A staging: ~512 VALU cyc/wave/step
//      (hand RNE bit-twiddle) -> ~16 cyc. Same RNE numerics.
//  (b) TLP instead of pipelining: BM 128->64 => grid 782->1564 blocks, LDS
//      64->48KB => 3 blocks/CU, ~12 waves/CU. m97/m114 implicit wave-level
//      overlap across resident blocks hides the barrier drain.

typedef __attribute__((ext_vector_type(8))) short bf16x8;
typedef __attribute__((ext_vector_type(8))) unsigned short ushort8;
typedef __attribute__((ext_vector_type(4))) float f32x4;

#define NN 50000
#define NE 800000
#define NF 512
#define NH 256
#define NL 128
#define NB ((NN + 255) / 256)

static __device__ __forceinline__ unsigned short f2bf(float f) {
  union { float f; unsigned int u; } v; v.f = f;
  unsigned int r = v.u + 0x7fffu + ((v.u >> 16) & 1u);   // RNE
  return (unsigned short)(r >> 16);
}
static __device__ __forceinline__ float bf2f(unsigned short u) {
  union { unsigned int u; float f; } v; v.u = (unsigned int)u << 16;
  return v.f;
}

// HW packed f32->bf16 (RNE), 2 elems / instruction. No builtin on gfx950 (m240);
// inline asm per T12 recipe. D[15:0]=cvt(lo), D[31:16]=cvt(hi).
static __device__ __forceinline__ unsigned int pkbf(float lo, float hi) {
  unsigned int r;
  asm("v_cvt_pk_bf16_f32 %0, %1, %2" : "=v"(r) : "v"(lo), "v"(hi));
  return r;
}
static __device__ __forceinline__ uint4 pk8(float4 a, float4 b) {
  uint4 o;
  o.x = pkbf(a.x, a.y); o.y = pkbf(a.z, a.w);
  o.z = pkbf(b.x, b.y); o.w = pkbf(b.z, b.w);
  return o;
}

// async global->LDS, 16B/lane; LDS dest must be wave-uniform base + lane*16.
static __device__ __forceinline__ void gll16(const void* g, void* l) {
  __builtin_amdgcn_global_load_lds(
      (const __attribute__((address_space(1))) void*)g,
      (__attribute__((address_space(3))) void*)l, 16, 0, 0);
}

// ---------------- CSR build ----------------
extern "C" __global__ void k_hist(const int* __restrict__ rows, int* __restrict__ counts, int n) {
  int i = blockIdx.x * 256 + threadIdx.x;
  if (i < n) atomicAdd(&counts[rows[i]], 1);
}

extern "C" __global__ __launch_bounds__(256) void k_blocksum(
    const int* __restrict__ counts, int* __restrict__ bsum, int n) {
  __shared__ int s[256];
  int t = threadIdx.x;
  int i = blockIdx.x * 256 + t;
  s[t] = (i < n) ? counts[i] : 0;
  __syncthreads();
  for (int off = 128; off > 0; off >>= 1) {
    if (t < off) s[t] += s[t + off];
    __syncthreads();
  }
  if (t == 0) bsum[blockIdx.x] = s[0];
}

extern "C" __global__ __launch_bounds__(256) void k_scansums(
    const int* __restrict__ bsum, int* __restrict__ bpre, int* __restrict__ rp, int nb, int n) {
  __shared__ int s[256];
  int t = threadIdx.x;
  int v = (t < nb) ? bsum[t] : 0;
  s[t] = v;
  __syncthreads();
  for (int off = 1; off < 256; off <<= 1) {
    int u = (t >= off) ? s[t - off] : 0;
    __syncthreads();
    s[t] += u;
    __syncthreads();
  }
  if (t < nb) bpre[t] = s[t] - v;
  if (t == 255) rp[n] = s[255];
}

extern "C" __global__ __launch_bounds__(256) void k_scanfin(
    const int* __restrict__ counts, const int* __restrict__ bpre,
    int* __restrict__ rp, int* __restrict__ cur, int n) {
  __shared__ int s[256];
  int t = threadIdx.x;
  int i = blockIdx.x * 256 + t;
  int c = (i < n) ? counts[i] : 0;
  s[t] = c;
  __syncthreads();
  for (int off = 1; off < 256; off <<= 1) {
    int u = (t >= off) ? s[t - off] : 0;
    __syncthreads();
    s[t] += u;
    __syncthreads();
  }
  if (i < n) {
    int e = bpre[blockIdx.x] + s[t] - c;
    rp[i] = e;
    cur[i] = e;
  }
}

extern "C" __global__ void k_scatter(const int* __restrict__ rows, const int* __restrict__ cols,
    const float* __restrict__ vals, int* __restrict__ cur, int2* __restrict__ ep, int n) {
  int i = blockIdx.x * 256 + threadIdx.x;
  if (i < n) {
    int p = atomicAdd(&cur[rows[i]], 1);
    int2 e; e.x = cols[i]; e.y = __float_as_int(vals[i]);
    ep[p] = e;
  }
}

// ---------------- weight transpose-cast: W [K][N] fp32 -> WT [N][K] bf16 ----------------
extern "C" __global__ void k_transcast(const float* __restrict__ w, unsigned short* __restrict__ wt,
                                       int K, int N) {
  int k = blockIdx.x; int n = threadIdx.x;
  wt[(size_t)n * K + k] = f2bf(w[(size_t)k * N + n]);
}

// ---------------- GEMM1: C[NN][256] = x[NN][512](fp32) * W1T[256][512]^T, bf16 out ----------------
// BM=64 BN=128 BK=64; grid 1564 blocks, LDS 48KB (3 blocks/CU). A staged via
// reg-prefetch + v_cvt_pk_bf16_f32 (swizzled ds_write); B via gll16 with
// swizzled GLOBAL source. One barrier per K-step.
extern "C" __global__ __launch_bounds__(256) void k_gemm1(
    const float* __restrict__ A, const unsigned short* __restrict__ BT,
    unsigned short* __restrict__ C) {
  __shared__ __align__(16) unsigned short sA[2][64 * 64];
  __shared__ __align__(16) unsigned short sB[2][128 * 64];
  int tid = threadIdx.x;
  int lane = tid & 63, wid = tid >> 6;
  int wm = (wid >> 1) * 32, wn = (wid & 1) * 64;
  int bm = blockIdx.x * 64, bn = blockIdx.y * 128;
  int l15 = lane & 15, lq = lane >> 4;
  int swzbase = l15 & 7;                  // row&7 for all fragment rows this lane reads
  f32x4 acc[2][4];
#pragma unroll
  for (int i = 0; i < 2; ++i)
#pragma unroll
    for (int j = 0; j < 4; ++j) acc[i][j] = (f32x4){0.f, 0.f, 0.f, 0.f};

  // A tile 64x64: 512 16B-units (bf16 space), 2/thread. unit u: row=u>>3, cu=u&7.
  // global fp32 source 32B at (bm+row, k0+cu*8); LDS dest unit cu^(row&7).
  // B tile 128x64: 1024 units, 4/thread via gll16, LDS contiguous, global unit
  // swizzled: g = (u&7)^(row&7).
  float4 ra[2][2];

  // ---- prologue: tile 0 ----
#pragma unroll
  for (int j = 0; j < 2; ++j) {
    int u = tid + 256 * j;
    int row = u >> 3, cu = u & 7;
    int ga = bm + row; if (ga >= NN) ga = NN - 1;
    const float* src = A + (size_t)ga * NF + cu * 8;
    ra[j][0] = ((const float4*)src)[0];
    ra[j][1] = ((const float4*)src)[1];
  }
#pragma unroll
  for (int j = 0; j < 4; ++j) {
    int u = tid + 256 * j;
    int row = u >> 3, cu = u & 7;
    int g = cu ^ (row & 7);
    gll16(BT + (size_t)(bn + row) * NF + g * 8, &sB[0][u * 8]);
  }
#pragma unroll
  for (int j = 0; j < 2; ++j) {
    int u = tid + 256 * j;
    int row = u >> 3, cu = u & 7;
    *(uint4*)(&sA[0][row * 64 + (cu ^ (row & 7)) * 8]) = pk8(ra[j][0], ra[j][1]);
  }
  __syncthreads();

  int cur = 0;
  for (int t = 0; t < NF / 64; ++t) {
    int k1 = (t + 1) * 64;
    if (t < NF / 64 - 1) {
      // issue next A tile into registers (overlaps the MFMA phase)
#pragma unroll
      for (int j = 0; j < 2; ++j) {
        int u = tid + 256 * j;
        int row = u >> 3, cu = u & 7;
        int ga = bm + row; if (ga >= NN) ga = NN - 1;
        const float* src = A + (size_t)ga * NF + k1 + cu * 8;
        ra[j][0] = ((const float4*)src)[0];
        ra[j][1] = ((const float4*)src)[1];
      }
      // issue next B tile into the other LDS buffer
#pragma unroll
      for (int j = 0; j < 4; ++j) {
        int u = tid + 256 * j;
        int row = u >> 3, cu = u & 7;
        int g = cu ^ (row & 7);
        gll16(BT + (size_t)(bn + row) * NF + k1 + g * 8, &sB[cur ^ 1][u * 8]);
      }
    }
    // compute on current buffers
#pragma unroll
    for (int ks = 0; ks < 64; ks += 32) {
      bf16x8 af[2], bfr[4];
#pragma unroll
      for (int tt = 0; tt < 2; ++tt) {
        int sz = (((ks >> 3) + lq) ^ swzbase) * 8;
        af[tt] = *(const bf16x8*)(&sA[cur][(wm + tt * 16 + l15) * 64 + sz]);
      }
#pragma unroll
      for (int tt = 0; tt < 4; ++tt) {
        int sz = (((ks >> 3) + lq) ^ swzbase) * 8;
        bfr[tt] = *(const bf16x8*)(&sB[cur][(wn + tt * 16 + l15) * 64 + sz]);
      }
#pragma unroll
      for (int mt = 0; mt < 2; ++mt)
#pragma unroll
        for (int nt = 0; nt < 4; ++nt)
          acc[mt][nt] = __builtin_amdgcn_mfma_f32_16x16x32_bf16(af[mt], bfr[nt], acc[mt][nt], 0, 0, 0);
    }
    // convert + write next A tile into the other buffer
    if (t < NF / 64 - 1) {
#pragma unroll
      for (int j = 0; j < 2; ++j) {
        int u = tid + 256 * j;
        int row = u >> 3, cu = u & 7;
        *(uint4*)(&sA[cur ^ 1][row * 64 + (cu ^ (row & 7)) * 8]) = pk8(ra[j][0], ra[j][1]);
      }
    }
    __syncthreads();
    cur ^= 1;
  }
#pragma unroll
  for (int mt = 0; mt < 2; ++mt) {
#pragma unroll
    for (int r = 0; r < 4; ++r) {
      int gr = bm + wm + mt * 16 + lq * 4 + r;
      if (gr < NN) {
#pragma unroll
        for (int nt = 0; nt < 4; ++nt) {
          int gc = bn + wn + nt * 16 + l15;
          C[(size_t)gr * NH + gc] = f2bf(acc[mt][nt][r]);
        }
      }
    }
  }
}

// ---------------- GEMM2: C[NN][128] = h[NN][256](bf16) * W2T[128][256]^T, bf16 out ----------------
// BM=64 BN=128 BK=64; both operands via gll16 with swizzled global source;
// double-buffer, one barrier per K-step.
extern "C" __global__ __launch_bounds__(256) void k_gemm2(
    const unsigned short* __restrict__ A, const unsigned short* __restrict__ BT,
    unsigned short* __restrict__ C) {
  __shared__ __align__(16) unsigned short sA[2][64 * 64];
  __shared__ __align__(16) unsigned short sB[2][128 * 64];
  int tid = threadIdx.x;
  int lane = tid & 63, wid = tid >> 6;
  int wm = (wid >> 1) * 32, wn = (wid & 1) * 64;
  int bm = blockIdx.x * 64;
  int l15 = lane & 15, lq = lane >> 4;
  int swzbase = l15 & 7;
  f32x4 acc[2][4];
#pragma unroll
  for (int i = 0; i < 2; ++i)
#pragma unroll
    for (int j = 0; j < 4; ++j) acc[i][j] = (f32x4){0.f, 0.f, 0.f, 0.f};

  // ---- prologue: tile 0 ----
#pragma unroll
  for (int j = 0; j < 2; ++j) {
    int u = tid + 256 * j;
    int row = u >> 3, cu = u & 7;
    int ga = bm + row; if (ga >= NN) ga = NN - 1;
    int g = cu ^ (row & 7);
    gll16(A + (size_t)ga * NH + g * 8, &sA[0][u * 8]);
  }
#pragma unroll
  for (int j = 0; j < 4; ++j) {
    int u = tid + 256 * j;
    int row = u >> 3, cu = u & 7;
    int g = cu ^ (row & 7);
    gll16(BT + (size_t)row * NH + g * 8, &sB[0][u * 8]);
  }
  __syncthreads();

  int cur = 0;
  for (int t = 0; t < NH / 64; ++t) {
    int k1 = (t + 1) * 64;
    if (t < NH / 64 - 1) {
#pragma unroll
      for (int j = 0; j < 2; ++j) {
        int u = tid + 256 * j;
        int row = u >> 3, cu = u & 7;
        int ga = bm + row; if (ga >= NN) ga = NN - 1;
        int g = cu ^ (row & 7);
        gll16(A + (size_t)ga * NH + k1 + g * 8, &sA[cur ^ 1][u * 8]);
      }
#pragma unroll
      for (int j = 0; j < 4; ++j) {
        int u = tid + 256 * j;
        int row = u >> 3, cu = u & 7;
        int g = cu ^ (row & 7);
        gll16(BT + (size_t)row * NH + k1 + g * 8, &sB[cur ^ 1][u * 8]);
      }
    }
#pragma unroll
    for (int ks = 0; ks < 64; ks += 32) {
      bf16x8 af[2], bfr[4];
#pragma unroll
      for (int tt = 0; tt < 2; ++tt)
        af[tt] = *(const bf16x8*)(&sA[cur][(wm + tt * 16 + l15) * 64 + (((ks >> 3) + lq) ^ swzbase) * 8]);
#pragma unroll
      for (int tt = 0; tt < 4; ++tt)
        bfr[tt] = *(const bf16x8*)(&sB[cur][(wn + tt * 16 + l15) * 64 + (((ks >> 3) + lq) ^ swzbase) * 8]);
#pragma unroll
      for (int mt = 0; mt < 2; ++mt)
#pragma unroll
        for (int nt = 0; nt < 4; ++nt)
          acc[mt][nt] = __builtin_amdgcn_mfma_f32_16x16x32_bf16(af[mt], bfr[nt], acc[mt][nt], 0, 0, 0);
    }
    __syncthreads();
    cur ^= 1;
  }
#pragma unroll
  for (int mt = 0; mt < 2; ++mt) {
#pragma unroll
    for (int r = 0; r < 4; ++r) {
      int gr = bm + wm + mt * 16 + lq * 4 + r;
      if (gr < NN) {
#pragma unroll
        for (int nt = 0; nt < 4; ++nt) {
          int gc = wn + nt * 16 + l15;
          C[(size_t)gr * NL + gc] = f2bf(acc[mt][nt][r]);
        }
      }
    }
  }
}

// ---------------- SpMM (CSR row-gather), bf16 src, unroll-8/4/1, fused bias+relu ----------------
extern "C" __global__ __launch_bounds__(256) void k_spmm256(
    const int* __restrict__ rp, const int2* __restrict__ ep,
    const unsigned short* __restrict__ src, const float* __restrict__ bias,
    ushort4* __restrict__ out) {
  int row = blockIdx.x * 4 + (threadIdx.x >> 6);
  int lane = threadIdx.x & 63;
  if (row >= NN) return;
  int e0 = __builtin_amdgcn_readfirstlane(rp[row]);
  int e1 = __builtin_amdgcn_readfirstlane(rp[row + 1]);
  const ushort4* srcv = (const ushort4*)src;
  float4 acc = {0.f, 0.f, 0.f, 0.f};
  int e = e0;
  for (; e + 8 <= e1; e += 8) {
    int2 p[8]; ushort4 g[8];
#pragma unroll
    for (int j = 0; j < 8; ++j) p[j] = ep[e + j];
#pragma unroll
    for (int j = 0; j < 8; ++j) g[j] = srcv[(size_t)p[j].x * (NH / 4) + lane];
#pragma unroll
    for (int j = 0; j < 8; ++j) {
      float v = __int_as_float(p[j].y);
      acc.x = fmaf(v, bf2f(g[j].x), acc.x); acc.y = fmaf(v, bf2f(g[j].y), acc.y);
      acc.z = fmaf(v, bf2f(g[j].z), acc.z); acc.w = fmaf(v, bf2f(g[j].w), acc.w);
    }
  }
  for (; e + 4 <= e1; e += 4) {
    int2 p[4]; ushort4 g[4];
#pragma unroll
    for (int j = 0; j < 4; ++j) p[j] = ep[e + j];
#pragma unroll
    for (int j = 0; j < 4; ++j) g[j] = srcv[(size_t)p[j].x * (NH / 4) + lane];
#pragma unroll
    for (int j = 0; j < 4; ++j) {
      float v = __int_as_float(p[j].y);
      acc.x = fmaf(v, bf2f(g[j].x), acc.x); acc.y = fmaf(v, bf2f(g[j].y), acc.y);
      acc.z = fmaf(v, bf2f(g[j].z), acc.z); acc.w = fmaf(v, bf2f(g[j].w), acc.w);
    }
  }
  for (; e < e1; ++e) {
    int2 p = ep[e];
    float v = __int_as_float(p.y);
    ushort4 g = srcv[(size_t)p.x * (NH / 4) + lane];
    acc.x = fmaf(v, bf2f(g.x), acc.x); acc.y = fmaf(v, bf2f(g.y), acc.y);
    acc.z = fmaf(v, bf2f(g.z), acc.z); acc.w = fmaf(v, bf2f(g.w), acc.w);
  }
  float4 b = ((const float4*)bias)[lane];
  ushort4 o;
  o.x = f2bf(fmaxf(acc.x + b.x, 0.f));
  o.y = f2bf(fmaxf(acc.y + b.y, 0.f));
  o.z = f2bf(fmaxf(acc.z + b.z, 0.f));
  o.w = f2bf(fmaxf(acc.w + b.w, 0.f));
  out[(size_t)row * (NH / 4) + lane] = o;
}

extern "C" __global__ __launch_bounds__(256) void k_spmm128(
    const int* __restrict__ rp, const int2* __restrict__ ep,
    const unsigned short* __restrict__ src, const float* __restrict__ bias,
    float2* __restrict__ out) {
  int row = blockIdx.x * 4 + (threadIdx.x >> 6);
  int lane = threadIdx.x & 63;
  if (row >= NN) return;
  int e0 = __builtin_amdgcn_readfirstlane(rp[row]);
  int e1 = __builtin_amdgcn_readfirstlane(rp[row + 1]);
  const ushort2* srcv = (const ushort2*)src;
  float2 acc = {0.f, 0.f};
  int e = e0;
  for (; e + 8 <= e1; e += 8) {
    int2 p[8]; ushort2 g[8];
#pragma unroll
    for (int j = 0; j < 8; ++j) p[j] = ep[e + j];
#pragma unroll
    for (int j = 0; j < 8; ++j) g[j] = srcv[(size_t)p[j].x * (NL / 2) + lane];
#pragma unroll
    for (int j = 0; j < 8; ++j) {
      float v = __int_as_float(p[j].y);
      acc.x = fmaf(v, bf2f(g[j].x), acc.x); acc.y = fmaf(v, bf2f(g[j].y), acc.y);
    }
  }
  for (; e + 4 <= e1; e += 4) {
    int2 p[4]; ushort2 g[4];
#pragma unroll
    for (int j = 0; j < 4; ++j) p[j] = ep[e + j];
#pragma unroll
    for (int j = 0; j < 4; ++j) g[j] = srcv[(size_t)p[j].x * (NL / 2) + lane];
#pragma unroll
    for (int j = 0; j < 4; ++j) {
      float v = __int_as_float(p[j].y);
      acc.x = fmaf(v, bf2f(g[j].x), acc.x); acc.y = fmaf(v, bf2f(g[j].y), acc.y);
    }
  }
  for (; e < e1; ++e) {
    int2 p = ep[e];
    float v = __int_as_float(p.y);
    ushort2 g = srcv[(size_t)p.x * (NL / 2) + lane];
    acc.x = fmaf(v, bf2f(g.x), acc.x); acc.y = fmaf(v, bf2f(g.y), acc.y);
  }
  float2 b = ((const float2*)bias)[lane];
  float2 o;
  o.x = fmaxf(acc.x + b.x, 0.f);
  o.y = fmaxf(acc.y + b.y, 0.f);
  out[(size_t)row * (NL / 2) + lane] = o;
}

// ---------------- launch ----------------
extern "C" void kernel_launch(void* const* d_in, const int* in_sizes, int n_in,
                              void* d_out, int out_size, void* d_ws, size_t ws_size,
                              hipStream_t stream) {
  const float* x   = (const float*)d_in[0];
  const int* erow  = (const int*)d_in[1];
  const int* ecol  = (const int*)d_in[2];
  const float* ev  = (const float*)d_in[3];
  const float* W1  = (const float*)d_in[4];
  const float* b1  = (const float*)d_in[5];
  const float* W2  = (const float*)d_in[6];
  const float* b2  = (const float*)d_in[7];

  char* ws = (char*)d_ws;
  unsigned short* xwb = (unsigned short*)(ws + 0);           // 25,600,000 (x@W1 bf16)
  unsigned short* hbf = (unsigned short*)(ws + 25600000);    // 25,600,000 (h bf16)
  unsigned short* hwb = (unsigned short*)(ws + 51200000);    // 12,800,000 (h@W2 bf16)
  unsigned short* w1t = (unsigned short*)(ws + 64000000);    // 262,144
  unsigned short* w2t = (unsigned short*)(ws + 64262144);    // 65,536
  int* rp    = (int*)(ws + 64327680);                        // 200,704
  int* cur   = (int*)(ws + 64528384);                        // 200,704
  int* cnt   = (int*)(ws + 64729088);                        // 200,704
  int* bsum  = (int*)(ws + 64929792);                        // 1,024
  int* bpre  = (int*)(ws + 64930816);                        // 1,024
  int2* ep   = (int2*)(ws + 64931840);                       // 6,400,000

  // CSR build
  hipMemsetAsync(cnt, 0, NN * sizeof(int), stream);
  k_hist<<<NE / 256, 256, 0, stream>>>(erow, cnt, NE);
  k_blocksum<<<NB, 256, 0, stream>>>(cnt, bsum, NN);
  k_scansums<<<1, 256, 0, stream>>>(bsum, bpre, rp, NB, NN);
  k_scanfin<<<NB, 256, 0, stream>>>(cnt, bpre, rp, cur, NN);
  k_scatter<<<NE / 256, 256, 0, stream>>>(erow, ecol, ev, cur, ep, NE);

  // layer 1
  k_transcast<<<NF, NH, 0, stream>>>(W1, w1t, NF, NH);
  k_gemm1<<<dim3((NN + 63) / 64, NH / 128), 256, 0, stream>>>(x, w1t, xwb);
  k_spmm256<<<NN / 4, 256, 0, stream>>>(rp, ep, xwb, b1, (ushort4*)hbf);

  // layer 2
  k_transcast<<<NH, NL, 0, stream>>>(W2, w2t, NH, NL);
  k_gemm2<<<(NN + 63) / 64, 256, 0, stream>>>(hbf, w2t, hwb);
  k_spmm128<<<NN / 4, 256, 0, stream>>>(rp, ep, hwb, b2, (float2*)d_out);
}

// Round 3
// 376.144 us; speedup vs baseline: 1.0164x; 1.0115x over previous
//
#include <hip/hip_runtime.h>
#include <hip/hip_bf16.h>

// GCN encoder: z = relu(A @ relu(A @ (x@W1) + b1) @ W2 + b2)
// R9: gemm1 counted-vmcnt pipeline (T4). R8 post-mortem: VALU fix + occupancy
// both landed (VALUBusy 16->6, occ 17->29) yet dur 63->70us at 1.85 TB/s and
// ideal FETCH -> pure exposed HBM latency: __syncthreads drains vmcnt(0) every
// K-step, killing any prefetch (m99/m100/m218 mechanism). Now: raw s_barrier +
// hand-counted s_waitcnt vmcnt(N); A (HBM) 2-deep register prefetch (window
// ~1.5 steps ~= 900cy), B (L2-resident w1t) 1-deep gll16 (window ~1 step).
// Ledger (groups of 4 vm-ops, in-order retire): steady step t:
//   issueB(t+1) | loadA(t+2) | MFMA(t) | vm(8)->writeA(t+1) | vm(4)+lgkm->bar
// leaving A(t+2) in flight ACROSS the barrier. sched_barrier(0) pins order.

typedef __attribute__((ext_vector_type(8))) short bf16x8;
typedef __attribute__((ext_vector_type(8))) unsigned short ushort8;
typedef __attribute__((ext_vector_type(4))) float f32x4;

#define NN 50000
#define NE 800000
#define NF 512
#define NH 256
#define NL 128
#define NB ((NN + 255) / 256)

#define WAIT_VM(N) asm volatile("s_waitcnt vmcnt(" #N ")" ::: "memory")
#define WAIT_VM_LGKM(N) asm volatile("s_waitcnt vmcnt(" #N ") lgkmcnt(0)" ::: "memory")
#define SCHED_FENCE() __builtin_amdgcn_sched_barrier(0)
#define BARRIER() __builtin_amdgcn_s_barrier()

static __device__ __forceinline__ unsigned short f2bf(float f) {
  union { float f; unsigned int u; } v; v.f = f;
  unsigned int r = v.u + 0x7fffu + ((v.u >> 16) & 1u);   // RNE
  return (unsigned short)(r >> 16);
}
static __device__ __forceinline__ float bf2f(unsigned short u) {
  union { unsigned int u; float f; } v; v.u = (unsigned int)u << 16;
  return v.f;
}

// HW packed f32->bf16 (RNE), 2 elems / instruction (no builtin on gfx950).
static __device__ __forceinline__ unsigned int pkbf(float lo, float hi) {
  unsigned int r;
  asm("v_cvt_pk_bf16_f32 %0, %1, %2" : "=v"(r) : "v"(lo), "v"(hi));
  return r;
}
static __device__ __forceinline__ uint4 pk8(float4 a, float4 b) {
  uint4 o;
  o.x = pkbf(a.x, a.y); o.y = pkbf(a.z, a.w);
  o.z = pkbf(b.x, b.y); o.w = pkbf(b.z, b.w);
  return o;
}

// async global->LDS, 16B/lane; LDS dest must be wave-uniform base + lane*16.
static __device__ __forceinline__ void gll16(const void* g, void* l) {
  __builtin_amdgcn_global_load_lds(
      (const __attribute__((address_space(1))) void*)g,
      (__attribute__((address_space(3))) void*)l, 16, 0, 0);
}

// ---------------- CSR build ----------------
extern "C" __global__ void k_hist(const int* __restrict__ rows, int* __restrict__ counts, int n) {
  int i = blockIdx.x * 256 + threadIdx.x;
  if (i < n) atomicAdd(&counts[rows[i]], 1);
}

extern "C" __global__ __launch_bounds__(256) void k_blocksum(
    const int* __restrict__ counts, int* __restrict__ bsum, int n) {
  __shared__ int s[256];
  int t = threadIdx.x;
  int i = blockIdx.x * 256 + t;
  s[t] = (i < n) ? counts[i] : 0;
  __syncthreads();
  for (int off = 128; off > 0; off >>= 1) {
    if (t < off) s[t] += s[t + off];
    __syncthreads();
  }
  if (t == 0) bsum[blockIdx.x] = s[0];
}

extern "C" __global__ __launch_bounds__(256) void k_scansums(
    const int* __restrict__ bsum, int* __restrict__ bpre, int* __restrict__ rp, int nb, int n) {
  __shared__ int s[256];
  int t = threadIdx.x;
  int v = (t < nb) ? bsum[t] : 0;
  s[t] = v;
  __syncthreads();
  for (int off = 1; off < 256; off <<= 1) {
    int u = (t >= off) ? s[t - off] : 0;
    __syncthreads();
    s[t] += u;
    __syncthreads();
  }
  if (t < nb) bpre[t] = s[t] - v;
  if (t == 255) rp[n] = s[255];
}

extern "C" __global__ __launch_bounds__(256) void k_scanfin(
    const int* __restrict__ counts, const int* __restrict__ bpre,
    int* __restrict__ rp, int* __restrict__ cur, int n) {
  __shared__ int s[256];
  int t = threadIdx.x;
  int i = blockIdx.x * 256 + t;
  int c = (i < n) ? counts[i] : 0;
  s[t] = c;
  __syncthreads();
  for (int off = 1; off < 256; off <<= 1) {
    int u = (t >= off) ? s[t - off] : 0;
    __syncthreads();
    s[t] += u;
    __syncthreads();
  }
  if (i < n) {
    int e = bpre[blockIdx.x] + s[t] - c;
    rp[i] = e;
    cur[i] = e;
  }
}

extern "C" __global__ void k_scatter(const int* __restrict__ rows, const int* __restrict__ cols,
    const float* __restrict__ vals, int* __restrict__ cur, int2* __restrict__ ep, int n) {
  int i = blockIdx.x * 256 + threadIdx.x;
  if (i < n) {
    int p = atomicAdd(&cur[rows[i]], 1);
    int2 e; e.x = cols[i]; e.y = __float_as_int(vals[i]);
    ep[p] = e;
  }
}

// ---------------- weight transpose-cast: W [K][N] fp32 -> WT [N][K] bf16 ----------------
extern "C" __global__ void k_transcast(const float* __restrict__ w, unsigned short* __restrict__ wt,
                                       int K, int N) {
  int k = blockIdx.x; int n = threadIdx.x;
  wt[(size_t)n * K + k] = f2bf(w[(size_t)k * N + n]);
}

// ---------------- GEMM1: C[NN][256] = x[NN][512](fp32) * W1T[256][512]^T, bf16 out ----------------
// BM=64 BN=128 BK=64; counted-vmcnt pipeline, see header comment.
extern "C" __global__ __launch_bounds__(256) void k_gemm1(
    const float* __restrict__ A, const unsigned short* __restrict__ BT,
    unsigned short* __restrict__ C) {
  __shared__ __align__(16) unsigned short sA[2][64 * 64];
  __shared__ __align__(16) unsigned short sB[2][128 * 64];
  int tid = threadIdx.x;
  int lane = tid & 63, wid = tid >> 6;
  int wm = (wid >> 1) * 32, wn = (wid & 1) * 64;
  int bm = blockIdx.x * 64, bn = blockIdx.y * 128;
  int l15 = lane & 15, lq = lane >> 4;
  int swzbase = l15 & 7;
  f32x4 acc[2][4];
#pragma unroll
  for (int i = 0; i < 2; ++i)
#pragma unroll
    for (int j = 0; j < 4; ++j) acc[i][j] = (f32x4){0.f, 0.f, 0.f, 0.f};

  // A tile 64x64 bf16: 512 16B-units, 2/thread. unit u: row=u>>3, cu=u&7.
  // global fp32 source 32B at (bm+row, k+cu*8); LDS dest unit cu^(row&7).
  // B tile 128x64: 1024 units, 4/thread via gll16, LDS contiguous, global
  // unit swizzled g=(u&7)^(row&7).
  float4 ra[2][2][2];   // [set][unit][half] -- 2-deep A prefetch

  auto loadA = [&](int t, int set) {
#pragma unroll
    for (int j = 0; j < 2; ++j) {
      int u = tid + 256 * j;
      int row = u >> 3, cu = u & 7;
      int ga = bm + row; if (ga >= NN) ga = NN - 1;
      const float* src = A + (size_t)ga * NF + t * 64 + cu * 8;
      ra[set][j][0] = ((const float4*)src)[0];
      ra[set][j][1] = ((const float4*)src)[1];
    }
  };
  auto issueB = [&](int t) {
#pragma unroll
    for (int j = 0; j < 4; ++j) {
      int u = tid + 256 * j;
      int row = u >> 3, cu = u & 7;
      int g = cu ^ (row & 7);
      gll16(BT + (size_t)(bn + row) * NF + t * 64 + g * 8, &sB[t & 1][u * 8]);
    }
  };
  auto writeA = [&](int t, int set) {
#pragma unroll
    for (int j = 0; j < 2; ++j) {
      int u = tid + 256 * j;
      int row = u >> 3, cu = u & 7;
      *(uint4*)(&sA[t & 1][row * 64 + (cu ^ (row & 7)) * 8]) = pk8(ra[set][j][0], ra[set][j][1]);
    }
  };
  auto comp = [&](int t) {
#pragma unroll
    for (int ks = 0; ks < 64; ks += 32) {
      bf16x8 af[2], bfr[4];
#pragma unroll
      for (int tt = 0; tt < 2; ++tt) {
        int sz = (((ks >> 3) + lq) ^ swzbase) * 8;
        af[tt] = *(const bf16x8*)(&sA[t & 1][(wm + tt * 16 + l15) * 64 + sz]);
      }
#pragma unroll
      for (int tt = 0; tt < 4; ++tt) {
        int sz = (((ks >> 3) + lq) ^ swzbase) * 8;
        bfr[tt] = *(const bf16x8*)(&sB[t & 1][(wn + tt * 16 + l15) * 64 + sz]);
      }
#pragma unroll
      for (int mt = 0; mt < 2; ++mt)
#pragma unroll
        for (int nt = 0; nt < 4; ++nt)
          acc[mt][nt] = __builtin_amdgcn_mfma_f32_16x16x32_bf16(af[mt], bfr[nt], acc[mt][nt], 0, 0, 0);
    }
  };

  // ---- prologue ----
  loadA(0, 0);            // vm: [A0]
  SCHED_FENCE();
  issueB(0);              // vm: [A0,B0]
  issueB(1);              // vm: [A0,B0,B1]
  SCHED_FENCE();
  WAIT_VM(8);             // A0 done
  writeA(0, 0);           // -> sA[0]
  SCHED_FENCE();
  loadA(1, 1);            // vm: [B0,B1,A1]
  SCHED_FENCE();
  WAIT_VM_LGKM(8);        // B0 done, ds_writes drained; leaves [B1,A1]
  SCHED_FENCE();
  BARRIER();

  // ---- 8 K-steps ----
#pragma unroll
  for (int t = 0; t < 8; ++t) {
    if (t >= 1 && t <= 6) { issueB(t + 1); SCHED_FENCE(); }
    if (t <= 5) { loadA(t + 2, t & 1); SCHED_FENCE(); }
    comp(t);
    if (t <= 6) {
      // wait A(t+1) loads (leave newer B(t+1)/A(t+2) in flight where present)
      if (t == 0) { WAIT_VM(4); }        // [B1,A1,A2] -> leaves A2
      else if (t == 6) { WAIT_VM(4); }   // [A7,B7]    -> leaves B7
      else { WAIT_VM(8); }               // [A(t+1),B(t+1),A(t+2)] -> leaves 8
      writeA(t + 1, (t + 1) & 1);
      SCHED_FENCE();
      // barrier: B(t+1) done + ds_writes visible; A(t+2) stays in flight
      if (t == 6) { WAIT_VM_LGKM(0); } else { WAIT_VM_LGKM(4); }
      SCHED_FENCE();
      BARRIER();
    }
  }

#pragma unroll
  for (int mt = 0; mt < 2; ++mt) {
#pragma unroll
    for (int r = 0; r < 4; ++r) {
      int gr = bm + wm + mt * 16 + lq * 4 + r;
      if (gr < NN) {
#pragma unroll
        for (int nt = 0; nt < 4; ++nt) {
          int gc = bn + wn + nt * 16 + l15;
          C[(size_t)gr * NH + gc] = f2bf(acc[mt][nt][r]);
        }
      }
    }
  }
}

// ---------------- GEMM2: C[NN][128] = h[NN][256](bf16) * W2T[128][256]^T, bf16 out ----------------
// BM=64 BN=128 BK=64; both operands via gll16 with swizzled global source;
// double-buffer, one barrier per K-step.
extern "C" __global__ __launch_bounds__(256) void k_gemm2(
    const unsigned short* __restrict__ A, const unsigned short* __restrict__ BT,
    unsigned short* __restrict__ C) {
  __shared__ __align__(16) unsigned short sA[2][64 * 64];
  __shared__ __align__(16) unsigned short sB[2][128 * 64];
  int tid = threadIdx.x;
  int lane = tid & 63, wid = tid >> 6;
  int wm = (wid >> 1) * 32, wn = (wid & 1) * 64;
  int bm = blockIdx.x * 64;
  int l15 = lane & 15, lq = lane >> 4;
  int swzbase = l15 & 7;
  f32x4 acc[2][4];
#pragma unroll
  for (int i = 0; i < 2; ++i)
#pragma unroll
    for (int j = 0; j < 4; ++j) acc[i][j] = (f32x4){0.f, 0.f, 0.f, 0.f};

  // ---- prologue: tile 0 ----
#pragma unroll
  for (int j = 0; j < 2; ++j) {
    int u = tid + 256 * j;
    int row = u >> 3, cu = u & 7;
    int ga = bm + row; if (ga >= NN) ga = NN - 1;
    int g = cu ^ (row & 7);
    gll16(A + (size_t)ga * NH + g * 8, &sA[0][u * 8]);
  }
#pragma unroll
  for (int j = 0; j < 4; ++j) {
    int u = tid + 256 * j;
    int row = u >> 3, cu = u & 7;
    int g = cu ^ (row & 7);
    gll16(BT + (size_t)row * NH + g * 8, &sB[0][u * 8]);
  }
  __syncthreads();

  int cur = 0;
  for (int t = 0; t < NH / 64; ++t) {
    int k1 = (t + 1) * 64;
    if (t < NH / 64 - 1) {
#pragma unroll
      for (int j = 0; j < 2; ++j) {
        int u = tid + 256 * j;
        int row = u >> 3, cu = u & 7;
        int ga = bm + row; if (ga >= NN) ga = NN - 1;
        int g = cu ^ (row & 7);
        gll16(A + (size_t)ga * NH + k1 + g * 8, &sA[cur ^ 1][u * 8]);
      }
#pragma unroll
      for (int j = 0; j < 4; ++j) {
        int u = tid + 256 * j;
        int row = u >> 3, cu = u & 7;
        int g = cu ^ (row & 7);
        gll16(BT + (size_t)row * NH + k1 + g * 8, &sB[cur ^ 1][u * 8]);
      }
    }
#pragma unroll
    for (int ks = 0; ks < 64; ks += 32) {
      bf16x8 af[2], bfr[4];
#pragma unroll
      for (int tt = 0; tt < 2; ++tt)
        af[tt] = *(const bf16x8*)(&sA[cur][(wm + tt * 16 + l15) * 64 + (((ks >> 3) + lq) ^ swzbase) * 8]);
#pragma unroll
      for (int tt = 0; tt < 4; ++tt)
        bfr[tt] = *(const bf16x8*)(&sB[cur][(wn + tt * 16 + l15) * 64 + (((ks >> 3) + lq) ^ swzbase) * 8]);
#pragma unroll
      for (int mt = 0; mt < 2; ++mt)
#pragma unroll
        for (int nt = 0; nt < 4; ++nt)
          acc[mt][nt] = __builtin_amdgcn_mfma_f32_16x16x32_bf16(af[mt], bfr[nt], acc[mt][nt], 0, 0, 0);
    }
    __syncthreads();
    cur ^= 1;
  }
#pragma unroll
  for (int mt = 0; mt < 2; ++mt) {
#pragma unroll
    for (int r = 0; r < 4; ++r) {
      int gr = bm + wm + mt * 16 + lq * 4 + r;
      if (gr < NN) {
#pragma unroll
        for (int nt = 0; nt < 4; ++nt) {
          int gc = wn + nt * 16 + l15;
          C[(size_t)gr * NL + gc] = f2bf(acc[mt][nt][r]);
        }
      }
    }
  }
}

// ---------------- SpMM (CSR row-gather), bf16 src, unroll-8/4/1, fused bias+relu ----------------
extern "C" __global__ __launch_bounds__(256) void k_spmm256(
    const int* __restrict__ rp, const int2* __restrict__ ep,
    const unsigned short* __restrict__ src, const float* __restrict__ bias,
    ushort4* __restrict__ out) {
  int row = blockIdx.x * 4 + (threadIdx.x >> 6);
  int lane = threadIdx.x & 63;
  if (row >= NN) return;
  int e0 = __builtin_amdgcn_readfirstlane(rp[row]);
  int e1 = __builtin_amdgcn_readfirstlane(rp[row + 1]);
  const ushort4* srcv = (const ushort4*)src;
  float4 acc = {0.f, 0.f, 0.f, 0.f};
  int e = e0;
  for (; e + 8 <= e1; e += 8) {
    int2 p[8]; ushort4 g[8];
#pragma unroll
    for (int j = 0; j < 8; ++j) p[j] = ep[e + j];
#pragma unroll
    for (int j = 0; j < 8; ++j) g[j] = srcv[(size_t)p[j].x * (NH / 4) + lane];
#pragma unroll
    for (int j = 0; j < 8; ++j) {
      float v = __int_as_float(p[j].y);
      acc.x = fmaf(v, bf2f(g[j].x), acc.x); acc.y = fmaf(v, bf2f(g[j].y), acc.y);
      acc.z = fmaf(v, bf2f(g[j].z), acc.z); acc.w = fmaf(v, bf2f(g[j].w), acc.w);
    }
  }
  for (; e + 4 <= e1; e += 4) {
    int2 p[4]; ushort4 g[4];
#pragma unroll
    for (int j = 0; j < 4; ++j) p[j] = ep[e + j];
#pragma unroll
    for (int j = 0; j < 4; ++j) g[j] = srcv[(size_t)p[j].x * (NH / 4) + lane];
#pragma unroll
    for (int j = 0; j < 4; ++j) {
      float v = __int_as_float(p[j].y);
      acc.x = fmaf(v, bf2f(g[j].x), acc.x); acc.y = fmaf(v, bf2f(g[j].y), acc.y);
      acc.z = fmaf(v, bf2f(g[j].z), acc.z); acc.w = fmaf(v, bf2f(g[j].w), acc.w);
    }
  }
  for (; e < e1; ++e) {
    int2 p = ep[e];
    float v = __int_as_float(p.y);
    ushort4 g = srcv[(size_t)p.x * (NH / 4) + lane];
    acc.x = fmaf(v, bf2f(g.x), acc.x); acc.y = fmaf(v, bf2f(g.y), acc.y);
    acc.z = fmaf(v, bf2f(g.z), acc.z); acc.w = fmaf(v, bf2f(g.w), acc.w);
  }
  float4 b = ((const float4*)bias)[lane];
  ushort4 o;
  o.x = f2bf(fmaxf(acc.x + b.x, 0.f));
  o.y = f2bf(fmaxf(acc.y + b.y, 0.f));
  o.z = f2bf(fmaxf(acc.z + b.z, 0.f));
  o.w = f2bf(fmaxf(acc.w + b.w, 0.f));
  out[(size_t)row * (NH / 4) + lane] = o;
}

extern "C" __global__ __launch_bounds__(256) void k_spmm128(
    const int* __restrict__ rp, const int2* __restrict__ ep,
    const unsigned short* __restrict__ src, const float* __restrict__ bias,
    float2* __restrict__ out) {
  int row = blockIdx.x * 4 + (threadIdx.x >> 6);
  int lane = threadIdx.x & 63;
  if (row >= NN) return;
  int e0 = __builtin_amdgcn_readfirstlane(rp[row]);
  int e1 = __builtin_amdgcn_readfirstlane(rp[row + 1]);
  const ushort2* srcv = (const ushort2*)src;
  float2 acc = {0.f, 0.f};
  int e = e0;
  for (; e + 8 <= e1; e += 8) {
    int2 p[8]; ushort2 g[8];
#pragma unroll
    for (int j = 0; j < 8; ++j) p[j] = ep[e + j];
#pragma unroll
    for (int j = 0; j < 8; ++j) g[j] = srcv[(size_t)p[j].x * (NL / 2) + lane];
#pragma unroll
    for (int j = 0; j < 8; ++j) {
      float v = __int_as_float(p[j].y);
      acc.x = fmaf(v, bf2f(g[j].x), acc.x); acc.y = fmaf(v, bf2f(g[j].y), acc.y);
    }
  }
  for (; e + 4 <= e1; e += 4) {
    int2 p[4]; ushort2 g[4];
#pragma unroll
    for (int j = 0; j < 4; ++j) p[j] = ep[e + j];
#pragma unroll
    for (int j = 0; j < 4; ++j) g[j] = srcv[(size_t)p[j].x * (NL / 2) + lane];
#pragma unroll
    for (int j = 0; j < 4; ++j) {
      float v = __int_as_float(p[j].y);
      acc.x = fmaf(v, bf2f(g[j].x), acc.x); acc.y = fmaf(v, bf2f(g[j].y), acc.y);
    }
  }
  for (; e < e1; ++e) {
    int2 p = ep[e];
    float v = __int_as_float(p.y);
    ushort2 g = srcv[(size_t)p.x * (NL / 2) + lane];
    acc.x = fmaf(v, bf2f(g.x), acc.x); acc.y = fmaf(v, bf2f(g.y), acc.y);
  }
  float2 b = ((const float2*)bias)[lane];
  float2 o;
  o.x = fmaxf(acc.x + b.x, 0.f);
  o.y = fmaxf(acc.y + b.y, 0.f);
  out[(size_t)row * (NL / 2) + lane] = o;
}

// ---------------- launch ----------------
extern "C" void kernel_launch(void* const* d_in, const int* in_sizes, int n_in,
                              void* d_out, int out_size, void* d_ws, size_t ws_size,
                              hipStream_t stream) {
  const float* x   = (const float*)d_in[0];
  const int* erow  = (const int*)d_in[1];
  const int* ecol  = (const int*)d_in[2];
  const float* ev  = (const float*)d_in[3];
  const float* W1  = (const float*)d_in[4];
  const float* b1  = (const float*)d_in[5];
  const float* W2  = (const float*)d_in[6];
  const float* b2  = (const float*)d_in[7];

  char* ws = (char*)d_ws;
  unsigned short* xwb = (unsigned short*)(ws + 0);           // 25,600,000 (x@W1 bf16)
  unsigned short* hbf = (unsigned short*)(ws + 25600000);    // 25,600,000 (h bf16)
  unsigned short* hwb = (unsigned short*)(ws + 51200000);    // 12,800,000 (h@W2 bf16)
  unsigned short* w1t = (unsigned short*)(ws + 64000000);    // 262,144
  unsigned short* w2t = (unsigned short*)(ws + 64262144);    // 65,536
  int* rp    = (int*)(ws + 64327680);                        // 200,704
  int* cur   = (int*)(ws + 64528384);                        // 200,704
  int* cnt   = (int*)(ws + 64729088);                        // 200,704
  int* bsum  = (int*)(ws + 64929792);                        // 1,024
  int* bpre  = (int*)(ws + 64930816);                        // 1,024
  int2* ep   = (int2*)(ws + 64931840);                       // 6,400,000

  // CSR build
  hipMemsetAsync(cnt, 0, NN * sizeof(int), stream);
  k_hist<<<NE / 256, 256, 0, stream>>>(erow, cnt, NE);
  k_blocksum<<<NB, 256, 0, stream>>>(cnt, bsum, NN);
  k_scansums<<<1, 256, 0, stream>>>(bsum, bpre, rp, NB, NN);
  k_scanfin<<<NB, 256, 0, stream>>>(cnt, bpre, rp, cur, NN);
  k_scatter<<<NE / 256, 256, 0, stream>>>(erow, ecol, ev, cur, ep, NE);

  // layer 1
  k_transcast<<<NF, NH, 0, stream>>>(W1, w1t, NF, NH);
  k_gemm1<<<dim3((NN + 63) / 64, NH / 128), 256, 0, stream>>>(x, w1t, xwb);
  k_spmm256<<<NN / 4, 256, 0, stream>>>(rp, ep, xwb, b1, (ushort4*)hbf);

  // layer 2
  k_transcast<<<NH, NL, 0, stream>>>(W2, w2t, NH, NL);
  k_gemm2<<<(NN + 63) / 64, 256, 0, stream>>>(hbf, w2t, hwb);
  k_spmm128<<<NN / 4, 256, 0, stream>>>(rp, ep, hwb, b2, (float2*)d_out);
}